// Round 8
// baseline (381.654 us; speedup 1.0000x reference)
//
#include <hip/hip_runtime.h>
#include <hip/hip_bf16.h>

typedef __attribute__((ext_vector_type(8))) short bf16x8;
typedef __attribute__((ext_vector_type(4))) float f32x4;

#define BSHIFT 8          // cols per bucket = 256
#define BW 256
#define NSTR 8            // stripes (XCDs)
#define BCAP 768          // records per (bucket,stripe) stream; mean ~511
#define LCAP 24           // LDS records per bucket per round
#define KEDGE 16          // edges per thread per round (4096/block-round)

__device__ __forceinline__ float lk(float v) { return v > 0.f ? v : 0.01f * v; }

__device__ __forceinline__ short f2b(float v) {
  union { __hip_bfloat16 h; short s; } u;
  u.h = __float2bfloat16(v);
  return u.s;
}
__device__ __forceinline__ float loadF(const void* p, size_t i, int f32) {
  return f32 ? ((const float*)p)[i]
             : __bfloat162float(((const __hip_bfloat16*)p)[i]);
}
__device__ __forceinline__ void storeF(void* p, size_t i, int f32, float v) {
  if (f32) ((float*)p)[i] = v;
  else     ((__hip_bfloat16*)p)[i] = __float2bfloat16(v);
}
// bf16 pair (u32) -> two floats via bit ops (no cvt instruction)
__device__ __forceinline__ float blo(unsigned u) {
  union { unsigned u; float f; } c; c.u = u << 16; return c.f;
}
__device__ __forceinline__ float bhi(unsigned u) {
  union { unsigned u; float f; } c; c.u = u & 0xffff0000u; return c.f;
}

// ---- dtype detection (device-side, graph-safe) ------------------------------
__global__ void detect_kernel(const unsigned short* __restrict__ x,
                              const int* __restrict__ ei, int* __restrict__ flags) {
  int t = threadIdx.x;
  unsigned short u = x[t];
  int ex = (u >> 7) & 0xFF;
  if (ex >= 0xC0) atomicOr(&flags[0], 1);          // fp32 viewed as bf16 -> wild exps
  if (t < 128 && ei[2 * t + 1] != 0) atomicOr(&flags[1], 1);  // nonzero -> int32
}

// ---- pack all 4 weight matrices in ONE launch -------------------------------
// W [K,N] row-major -> MFMA B-fragment layout (bf16)
__global__ __launch_bounds__(64) void pack_all(const void* __restrict__ W1,
                                               const void* __restrict__ W2,
                                               const void* __restrict__ G1,
                                               const void* __restrict__ G2,
                                               __hip_bfloat16* __restrict__ P1,
                                               __hip_bfloat16* __restrict__ P2,
                                               __hip_bfloat16* __restrict__ PG1,
                                               __hip_bfloat16* __restrict__ PG2,
                                               const int* __restrict__ flags) {
  int f32 = flags[0] != 0;
  int b = blockIdx.x;
  const void* W; __hip_bfloat16* P; int KS, N, ks, ct;
  if (b < 64)      { W = W1; P = P1;  KS = 8; N = 128; int c = b;      ks = c & 7; ct = c >> 3; }
  else if (b < 80) { W = W2; P = P2;  KS = 4; N = 64;  int c = b - 64; ks = c & 3; ct = c >> 2; }
  else if (b < 88) { W = G1; P = PG1; KS = 2; N = 64;  int c = b - 80; ks = c & 1; ct = c >> 1; }
  else             { W = G2; P = PG2; KS = 2; N = 64;  int c = b - 88; ks = c & 1; ct = c >> 1; }
  int lane = threadIdx.x;
  int g = lane >> 4, m = lane & 15;
  size_t base = ((size_t)(ct * KS + ks) * 64 + (size_t)lane) * 8;
#pragma unroll
  for (int j = 0; j < 8; ++j)
    P[base + j] = __float2bfloat16(
        loadF(W, (size_t)(ks * 32 + g * 8 + j) * N + (size_t)(ct * 16 + m), f32));
}

// ---- tiled GEMM: one 32-row tile per block, bf16 LDS, XOR swizzle -----------
// LDS always holds bf16 with per-16B-chunk XOR swizzle (chunk ^= row&7) --
// conflict-free for the frag read pattern. fp32 A (AMODE=1 + flag): reg-stage
// -> cvt once -> swizzled ds_write_b128. bf16 A: global_load_lds with
// pre-swizzled global source (linear LDS dest, rule 21).
template <int KS, int CT, int AMODE>
__global__ __launch_bounds__(256) void gemm_bt(const void* __restrict__ A,
                                               const __hip_bfloat16* __restrict__ Bp,
                                               const void* __restrict__ bias,
                                               void* __restrict__ Out, int out_bf16,
                                               __hip_bfloat16* __restrict__ Yout,
                                               const float* __restrict__ dinv,
                                               int M, int N, int act,
                                               const int* __restrict__ flags) {
  constexpr int K = KS * 32;
  constexpr int CPR = K / 8;            // bf16 16B chunks per row
  __shared__ char tile[32 * K * 2];
  int f32 = AMODE ? (flags[0] != 0) : 0;
  int tid = threadIdx.x;
  int lane = tid & 63;
  int w = tid >> 6;                     // wave id = col partition
  int m = lane & 15, g = lane >> 4;
  int row0 = blockIdx.x << 5;

  bool done = false;
  if constexpr (AMODE) {
    if (f32) {
      constexpr int PP = K / 64;        // 32B chunk-pairs per thread
      float4 sr[2 * PP];
#pragma unroll
      for (int j = 0; j < PP; ++j) {
        int q = j * 256 + tid;          // flat chunk index (== bf16 chunk)
        int r = q / CPR, pc = q - r * CPR;
        int gr = row0 + r; if (gr >= M) gr = M - 1;
        const float* src = (const float*)A + (size_t)gr * K + (size_t)pc * 8;
        sr[2 * j]     = *(const float4*)src;
        sr[2 * j + 1] = *(const float4*)(src + 4);
      }
#pragma unroll
      for (int j = 0; j < PP; ++j) {
        int q = j * 256 + tid;
        int r = q / CPR, pc = q - r * CPR;
        bf16x8 ov;
        ov[0] = f2b(sr[2 * j].x);     ov[1] = f2b(sr[2 * j].y);
        ov[2] = f2b(sr[2 * j].z);     ov[3] = f2b(sr[2 * j].w);
        ov[4] = f2b(sr[2 * j + 1].x); ov[5] = f2b(sr[2 * j + 1].y);
        ov[6] = f2b(sr[2 * j + 1].z); ov[7] = f2b(sr[2 * j + 1].w);
        *(bf16x8*)(tile + (size_t)r * (K * 2) + (size_t)((pc ^ (r & 7)) * 16)) = ov;
      }
      done = true;
    }
  }
  if (!done) {                          // bf16 input: async global->LDS
    constexpr int PERW = 32 * CPR / 4;  // chunks per wave
#pragma unroll
    for (int i = 0; i < PERW; i += 64) {
      int p = w * PERW + i + lane;
      int r = p / CPR, pc = p - r * CPR;
      int gr = row0 + r; if (gr >= M) gr = M - 1;
      const char* src = (const char*)A + (size_t)gr * (K * 2) +
                        (size_t)((pc ^ (r & 7)) * 16);
      char* dst = tile + (size_t)(w * PERW + i) * 16;   // wave-uniform base
      __builtin_amdgcn_global_load_lds(
          (const __attribute__((address_space(1))) void*)src,
          (__attribute__((address_space(3))) void*)dst, 16, 0, 0);
    }
  }
  __syncthreads();

  const __hip_bfloat16* bbase = Bp + ((size_t)(w * CT) * KS * 64 + (size_t)lane) * 8;
  f32x4 accs[2][CT];
#pragma unroll
  for (int tt = 0; tt < 2; ++tt)
#pragma unroll
    for (int cc = 0; cc < CT; ++cc) accs[tt][cc] = (f32x4){0, 0, 0, 0};

#pragma unroll
  for (int ks = 0; ks < KS; ++ks) {
    bf16x8 a[2];
#pragma unroll
    for (int tt = 0; tt < 2; ++tt) {
      int r = tt * 16 + m;
      int c = ks * 4 + g;
      a[tt] = *(const bf16x8*)(tile + (size_t)r * (K * 2) +
                               (size_t)((c ^ (r & 7)) * 16));
    }
    const __hip_bfloat16* bb = bbase + (size_t)ks * 64 * 8;
#pragma unroll
    for (int cc = 0; cc < CT; ++cc) {
      bf16x8 b = *(const bf16x8*)(bb + (size_t)cc * KS * 64 * 8);
#pragma unroll
      for (int tt = 0; tt < 2; ++tt)
        accs[tt][cc] = __builtin_amdgcn_mfma_f32_16x16x32_bf16(a[tt], b, accs[tt][cc], 0, 0, 0);
    }
  }

  // epilogue
  float bv[CT];
#pragma unroll
  for (int cc = 0; cc < CT; ++cc)
    bv[cc] = bias ? loadF(bias, (size_t)((w * CT + cc) * 16 + m), flags[0] != 0) : 0.f;
#pragma unroll
  for (int tt = 0; tt < 2; ++tt) {
#pragma unroll
    for (int r = 0; r < 4; ++r) {
      int ro = row0 + tt * 16 + g * 4 + r;
      if (ro < M) {
        float di = Yout ? dinv[ro] : 0.f;
#pragma unroll
        for (int cc = 0; cc < CT; ++cc) {
          int col = (w * CT + cc) * 16 + m;
          float v = accs[tt][cc][r] + bv[cc];
          if (act) v = lk(v);
          if (Out) {
            if (out_bf16) ((__hip_bfloat16*)Out)[(size_t)ro * N + col] = __float2bfloat16(v);
            else          ((float*)Out)[(size_t)ro * N + col] = v;
          }
          if (Yout) Yout[(size_t)ro * N + col] = __float2bfloat16(v * di);
        }
      }
    }
  }
}

// ---- CSR build pass A: LDS-staged binning, batched stream flush -------------
// LDS: bcnt[NB] | gbase[NB] | bins[NB*LCAP] (int2)
__global__ __launch_bounds__(256) void bin_kernel(const int* __restrict__ ei,
                                                  int* __restrict__ cur,
                                                  int2* __restrict__ rec,
                                                  int E, int NB,
                                                  const int* __restrict__ flags) {
  extern __shared__ int lds[];
  int* bcnt = lds;
  int* gbase = lds + NB;
  int2* bins = (int2*)(lds + 2 * NB);
  int i64 = flags[1] == 0;
  // real XCD id (hwreg 20); any value is correctness-safe after &7
  int stripe = __builtin_amdgcn_s_getreg(63508) & (NSTR - 1);
  int t = threadIdx.x;
  const int perRound = 256 * KEDGE;
  for (int base = blockIdx.x * perRound; base < E; base += gridDim.x * perRound) {
    for (int b = t; b < NB; b += 256) bcnt[b] = 0;
    __syncthreads();
    // bin into LDS
#pragma unroll 1
    for (int k = 0; k < KEDGE; ++k) {
      int i = base + k * 256 + t;
      if (i < E) {
        int r, c;
        if (i64) {
          r = ((const int2*)ei)[i].x;            // int64 low word
          c = ((const int2*)ei)[(size_t)E + i].x;
        } else {
          r = ei[i];
          c = ei[(size_t)E + i];
        }
        int b = c >> BSHIFT;
        int pos = atomicAdd(&bcnt[b], 1);
        if (pos < LCAP) {
          bins[b * LCAP + pos] = make_int2(r, c);
        } else {                                   // rare overflow: direct append
          int bs = b * NSTR + stripe;
          int slot = atomicAdd(&cur[bs], 1);
          if (slot < BCAP) rec[(size_t)bs * BCAP + slot] = make_int2(r, c);
        }
      }
    }
    __syncthreads();
    // reserve stream ranges (parallel atomics, no serialized chain)
    for (int b = t; b < NB; b += 256) {
      int n = min(bcnt[b], LCAP);
      if (n > 0) gbase[b] = atomicAdd(&cur[b * NSTR + stripe], n);
    }
    __syncthreads();
    // contiguous copy LDS -> stream
    int lane = t & 63, w = t >> 6;
    for (int b = w; b < NB; b += 4) {
      int n = min(bcnt[b], LCAP);
      if (n == 0) continue;
      int gb = gbase[b];
      size_t sb = (size_t)(b * NSTR + stripe) * BCAP;
      if (lane < n && gb + lane < BCAP)
        rec[sb + gb + lane] = bins[b * LCAP + lane];
    }
    __syncthreads();
  }
}

// Pass B: one block per bucket, 512 threads. Inline global prefix (replaces
// the separate bucket_scan launch): base_b = sum_{i < b*NSTR} min(cur[i],BCAP),
// computed per block from the L2-hot cur array + LDS tree reduce.
__global__ __launch_bounds__(512) void place_kernel(const int2* __restrict__ rec,
                                                    const int* __restrict__ cur,
                                                    int* __restrict__ rowptr,
                                                    int* __restrict__ csr,
                                                    float* __restrict__ dinv, int Nn) {
  int b = blockIdx.x;
  int lo = b << BSHIFT;
  int t = threadIdx.x;
  __shared__ int cnt[BW];
  __shared__ int sc[BW];
  __shared__ int cursor[BW];
  __shared__ int red[512];
  int part = 0;
  for (int i = t; i < b * NSTR; i += 512) part += min(cur[i], BCAP);
  red[t] = part;
  if (t < BW) cnt[t] = 0;
  __syncthreads();
  for (int o = 256; o > 0; o >>= 1) {
    if (t < o) red[t] += red[t + o];
    __syncthreads();
  }
  int base = red[0];                    // global segment base for this bucket
#pragma unroll 1
  for (int s = 0; s < NSTR; ++s) {
    int n = min(cur[b * NSTR + s], BCAP);
    const int2* rp = rec + (size_t)(b * NSTR + s) * BCAP;
    for (int j = t; j < n; j += 512) atomicAdd(&cnt[rp[j].y - lo], 1);
  }
  __syncthreads();
  int v = 0;
  if (t < BW) { v = cnt[t]; sc[t] = v; }
  __syncthreads();
  for (int o = 1; o < BW; o <<= 1) {
    int a = (t >= o && t < BW) ? sc[t - o] : 0;
    __syncthreads();
    if (t < BW) sc[t] += a;
    __syncthreads();
  }
  if (t < BW) {
    int col = lo + t;
    if (col < Nn) {
      rowptr[col] = base + sc[t];               // segment END
      dinv[col] = rsqrtf((float)v + 1.0f);
    }
    cursor[t] = base + sc[t] - v;               // segment start
  }
  __syncthreads();
#pragma unroll 1
  for (int s = 0; s < NSTR; ++s) {
    int n = min(cur[b * NSTR + s], BCAP);
    const int2* rp = rec + (size_t)(b * NSTR + s) * BCAP;
    for (int j = t; j < n; j += 512) {
      int2 e = rp[j];
      int pos = atomicAdd(&cursor[e.y - lo], 1);
      csr[pos] = e.x;
    }
  }
}

// ---- pull-mode aggregation + self-term + bias + leaky, fused ----------------
// Half-wave (32 lanes) per node. Neighbor indices read DIRECTLY per lane from
// csr (same address within a half -> HW broadcast, L1-hot, 8 loads share one
// address register via immediate offsets) -- no shfl on the address path.
// Self term uses y[node]*di == xw*di*di. Optionally reduces edge-head scores
// ssrc[n]=h[n].wp1, sdst[n]=h[n].wp2.
__global__ __launch_bounds__(256) void gather_kernel(const __hip_bfloat16* __restrict__ y,
                                                     const int* __restrict__ csr,
                                                     const int* __restrict__ rowptr,
                                                     const float* __restrict__ dinv,
                                                     const void* __restrict__ bias,
                                                     void* __restrict__ outp, size_t obase,
                                                     int out_use_flag, int Nn,
                                                     float* __restrict__ ssrc,
                                                     float* __restrict__ sdst,
                                                     const void* __restrict__ Wp,
                                                     const int* __restrict__ flags) {
  int f32 = flags[0] != 0;
  int of32 = out_use_flag ? f32 : 0;    // intermediate h3 stored bf16
  int lane = threadIdx.x & 63;
  int w = (blockIdx.x * blockDim.x + threadIdx.x) >> 6;
  if (2 * w >= Nn) return;
  int half = lane >> 5;                 // which node of the pair
  int hl = lane & 31;                   // feature-pair index (f = 2*hl)
  int node = 2 * w + half;
  int alive = node < Nn;
  int nd = alive ? node : Nn - 1;       // clamp for safe loads
  int s = (nd == 0) ? 0 : rowptr[nd - 1];
  int e = rowptr[nd];
  if (!alive) e = s;
  const unsigned* yu = (const unsigned*)y;    // row = 32 bf16-pairs
  float p0a = 0, p1a = 0, p0b = 0, p1b = 0;
  float p0c = 0, p1c = 0, p0d = 0, p1d = 0;
  int j = s;
  for (; j + 8 <= e; j += 8) {
    int r0 = csr[j + 0];
    int r1 = csr[j + 1];
    int r2 = csr[j + 2];
    int r3 = csr[j + 3];
    int r4 = csr[j + 4];
    int r5 = csr[j + 5];
    int r6 = csr[j + 6];
    int r7 = csr[j + 7];
    unsigned u0 = yu[(unsigned)r0 * 32u + hl];
    unsigned u1 = yu[(unsigned)r1 * 32u + hl];
    unsigned u2 = yu[(unsigned)r2 * 32u + hl];
    unsigned u3 = yu[(unsigned)r3 * 32u + hl];
    unsigned u4 = yu[(unsigned)r4 * 32u + hl];
    unsigned u5 = yu[(unsigned)r5 * 32u + hl];
    unsigned u6 = yu[(unsigned)r6 * 32u + hl];
    unsigned u7 = yu[(unsigned)r7 * 32u + hl];
    p0a += blo(u0); p1a += bhi(u0);
    p0b += blo(u1); p1b += bhi(u1);
    p0c += blo(u2); p1c += bhi(u2);
    p0d += blo(u3); p1d += bhi(u3);
    p0a += blo(u4); p1a += bhi(u4);
    p0b += blo(u5); p1b += bhi(u5);
    p0c += blo(u6); p1c += bhi(u6);
    p0d += blo(u7); p1d += bhi(u7);
  }
  for (; j + 4 <= e; j += 4) {
    int r0 = csr[j + 0];
    int r1 = csr[j + 1];
    int r2 = csr[j + 2];
    int r3 = csr[j + 3];
    unsigned u0 = yu[(unsigned)r0 * 32u + hl];
    unsigned u1 = yu[(unsigned)r1 * 32u + hl];
    unsigned u2 = yu[(unsigned)r2 * 32u + hl];
    unsigned u3 = yu[(unsigned)r3 * 32u + hl];
    p0a += blo(u0); p1a += bhi(u0);
    p0b += blo(u1); p1b += bhi(u1);
    p0c += blo(u2); p1c += bhi(u2);
    p0d += blo(u3); p1d += bhi(u3);
  }
  for (; j < e; ++j) {
    int r0 = csr[j];
    unsigned u0 = yu[(unsigned)r0 * 32u + hl];
    p0a += blo(u0); p1a += bhi(u0);
  }
  float acc0 = (p0a + p0b) + (p0c + p0d);
  float acc1 = (p1a + p1b) + (p1c + p1d);
  unsigned un = yu[(unsigned)nd * 32u + hl];   // self term: y[node]*di
  acc0 += blo(un); acc1 += bhi(un);
  float di = dinv[nd];
  int f = hl * 2;
  float v0 = lk(di * acc0 + loadF(bias, (size_t)f, f32));
  float v1 = lk(di * acc1 + loadF(bias, (size_t)(f + 1), f32));
  if (alive) {
    if (of32) {
      *(float2*)((float*)outp + obase + (size_t)node * 64 + f) = make_float2(v0, v1);
    } else {
      union { unsigned u; unsigned short ss[2]; } pk;
      pk.ss[0] = (unsigned short)f2b(v0);
      pk.ss[1] = (unsigned short)f2b(v1);
      *(unsigned*)((__hip_bfloat16*)outp + obase + (size_t)node * 64 + f) = pk.u;
    }
  }
  if (ssrc) {
    float q1 = v0 * loadF(Wp, (size_t)f, f32) + v1 * loadF(Wp, (size_t)(f + 1), f32);
    float q2 = v0 * loadF(Wp, (size_t)(64 + f), f32) + v1 * loadF(Wp, (size_t)(65 + f), f32);
#pragma unroll
    for (int o = 16; o > 0; o >>= 1) {        // reduce within each 32-lane half
      q1 += __shfl_down(q1, o, 64);
      q2 += __shfl_down(q2, o, 64);
    }
    if (hl == 0 && alive) { ssrc[node] = q1; sdst[node] = q2; }
  }
}

// ---- edge scoring head: one THREAD per edge, scores precomputed -------------
__global__ __launch_bounds__(256) void edge_head_kernel(void* __restrict__ dout,
                                                        const int* __restrict__ eli,
                                                        const void* __restrict__ ea,
                                                        const float* __restrict__ ssrc,
                                                        const float* __restrict__ sdst,
                                                        const void* __restrict__ Wp,
                                                        const void* __restrict__ bp,
                                                        int EL, const int* __restrict__ flags) {
  int f32 = flags[0] != 0;
  int i64 = flags[1] == 0;
  int tid = blockIdx.x * blockDim.x + threadIdx.x;
  if (tid >= EL) return;
  int s, d;
  if (i64) {
    s = ((const int2*)eli)[tid].x;              // int64 low word, single 8B load
    d = ((const int2*)eli)[(size_t)EL + tid].x;
  } else {
    s = eli[tid];
    d = eli[(size_t)EL + tid];
  }
  float acc = ssrc[s] + sdst[d] + loadF(bp, 0, f32);
  if (f32) {
    const float* eap = (const float*)ea + (size_t)tid * 8;
    float4 u0 = *(const float4*)eap;
    float4 u1 = *(const float4*)(eap + 4);
    acc += u0.x * loadF(Wp, 128, 1) + u0.y * loadF(Wp, 129, 1) +
           u0.z * loadF(Wp, 130, 1) + u0.w * loadF(Wp, 131, 1) +
           u1.x * loadF(Wp, 132, 1) + u1.y * loadF(Wp, 133, 1) +
           u1.z * loadF(Wp, 134, 1) + u1.w * loadF(Wp, 135, 1);
  } else {
    bf16x8 u = *(const bf16x8*)((const __hip_bfloat16*)ea + (size_t)tid * 8);
#pragma unroll
    for (int j = 0; j < 8; ++j) {
      union { short s; __hip_bfloat16 h; } cv; cv.s = u[j];
      acc += __bfloat162float(cv.h) * loadF(Wp, (size_t)(128 + j), 0);
    }
  }
  storeF(dout, (size_t)tid, f32, acc);
}

extern "C" void kernel_launch(void* const* d_in, const int* in_sizes, int n_in,
                              void* d_out, int out_size, void* d_ws, size_t ws_size,
                              hipStream_t stream) {
  const void* x   = d_in[0];
  const int* ei   = (const int*)d_in[1];
  const int* eli  = (const int*)d_in[2];
  const void* ea  = d_in[3];
  const void* W1  = d_in[4];
  const void* b1  = d_in[5];
  const void* W2  = d_in[6];
  const void* b2  = d_in[7];
  const void* Wg1 = d_in[8];
  const void* bg1 = d_in[9];
  const void* Wg2 = d_in[10];
  const void* bg2 = d_in[11];
  const void* Wp  = d_in[12];
  const void* bp  = d_in[13];

  const int Nn = in_sizes[0] / 256;
  const int E  = in_sizes[1] / 2;
  const int EL = in_sizes[2] / 2;
  const int NB = (Nn + BW - 1) >> BSHIFT;       // col buckets

  char* ws = (char*)d_ws;
  size_t off = 0;
  auto take = [&](size_t bytes) -> char* {
    char* p = ws + off;
    off = (off + bytes + 255) & ~(size_t)255;
    return p;
  };
  int*   flags  = (int*)take(256);
  int*   cur    = (int*)take((size_t)NB * NSTR * 4);   // contiguous after flags
  int*   rowptr = (int*)take((size_t)Nn * 4);
  float* dinv   = (float*)take((size_t)Nn * 4);
  float* ssrc   = (float*)take((size_t)Nn * 4);
  float* sdst   = (float*)take((size_t)Nn * 4);
  int*   csr    = (int*)take((size_t)E * 4);
  int2*  rec    = (int2*)take((size_t)NB * NSTR * BCAP * 8);
  __hip_bfloat16* pW1 = (__hip_bfloat16*)take(256 * 128 * 2);
  __hip_bfloat16* pW2 = (__hip_bfloat16*)take(128 * 64 * 2);
  __hip_bfloat16* pG1 = (__hip_bfloat16*)take(64 * 64 * 2);
  __hip_bfloat16* pG2 = (__hip_bfloat16*)take(64 * 64 * 2);
  char* regionA = take((size_t)Nn * 128 * 4);   // h1(bf16) | y(bf16) at +Nn*256B
  char* regionB = take((size_t)Nn * 64 * 4);    // h2(bf16) | later h3(bf16)
  __hip_bfloat16* h1 = (__hip_bfloat16*)regionA;
  __hip_bfloat16* y = (__hip_bfloat16*)(regionA + (size_t)Nn * 64 * 4);
  __hip_bfloat16* h2 = (__hip_bfloat16*)regionB;
  __hip_bfloat16* h3 = (__hip_bfloat16*)regionB;

  // flags + cur are contiguous -> one memset covers both
  hipMemsetAsync(flags, 0, 256 + (((size_t)NB * NSTR * 4 + 255) & ~(size_t)255), stream);
  detect_kernel<<<1, 256, 0, stream>>>((const unsigned short*)x, ei, flags);

  pack_all<<<96, 64, 0, stream>>>(W1, W2, Wg1, Wg2, pW1, pW2, pG1, pG2, flags);

  // CSR build: LDS-staged binning -> place (scan fused into place)
  const int ldsbytes = NB * (8 + LCAP * 8);     // bcnt + gbase + bins
  const int nbin = (E + 256 * KEDGE - 1) / (256 * KEDGE);
  bin_kernel<<<nbin, 256, ldsbytes, stream>>>(ei, cur, rec, E, NB, flags);
  place_kernel<<<NB, 512, 0, stream>>>(rec, cur, rowptr, csr, dinv, Nn);

  // tiled GEMMs: block = 32 rows, 4 waves = 4 col-partitions
  const int tblocks = (Nn + 31) / 32;
  gemm_bt<8, 2, 1><<<tblocks, 256, 0, stream>>>(x, pW1, b1, h1, 1, nullptr, nullptr,
                                                Nn, 128, 1, flags);
  gemm_bt<4, 1, 0><<<tblocks, 256, 0, stream>>>(h1, pW2, b2, h2, 1, nullptr, nullptr,
                                                Nn, 64, 1, flags);

  // gathers: 2 nodes per wave (half-wave per node)
  const int gwaves = (Nn + 1) / 2;
  const int gblocks = (gwaves + 3) / 4;
  gemm_bt<2, 1, 0><<<tblocks, 256, 0, stream>>>(h2, pG1, nullptr, nullptr, 0, y, dinv,
                                                Nn, 64, 0, flags);
  gather_kernel<<<gblocks, 256, 0, stream>>>(y, csr, rowptr, dinv, bg1,
                                             h3, 0, 0, Nn,
                                             nullptr, nullptr, nullptr, flags);

  gemm_bt<2, 1, 0><<<tblocks, 256, 0, stream>>>(h3, pG2, nullptr, nullptr, 0, y, dinv,
                                                Nn, 64, 0, flags);
  gather_kernel<<<gblocks, 256, 0, stream>>>(y, csr, rowptr, dinv, bg2,
                                             d_out, (size_t)EL, 1, Nn,
                                             ssrc, sdst, Wp, flags);

  edge_head_kernel<<<(EL + 255) / 256, 256, 0, stream>>>(d_out, eli, ea, ssrc, sdst,
                                                         Wp, bp, EL, flags);
}

// Round 9
// 361.556 us; speedup vs baseline: 1.0556x; 1.0556x over previous
//
#include <hip/hip_runtime.h>
#include <hip/hip_bf16.h>

typedef __attribute__((ext_vector_type(8))) short bf16x8;
typedef __attribute__((ext_vector_type(4))) float f32x4;

#define BSHIFT 8          // cols per bucket = 256
#define BW 256
#define NSTR 8            // stripes (XCDs)
#define BCAP 768          // records per (bucket,stripe) stream; mean ~511
#define LCAP 24           // LDS records per bucket per round
#define KEDGE 16          // edges per thread per round (4096/block-round)

__device__ __forceinline__ float lk(float v) { return v > 0.f ? v : 0.01f * v; }

__device__ __forceinline__ short f2b(float v) {
  union { __hip_bfloat16 h; short s; } u;
  u.h = __float2bfloat16(v);
  return u.s;
}
__device__ __forceinline__ float loadF(const void* p, size_t i, int f32) {
  return f32 ? ((const float*)p)[i]
             : __bfloat162float(((const __hip_bfloat16*)p)[i]);
}
__device__ __forceinline__ void storeF(void* p, size_t i, int f32, float v) {
  if (f32) ((float*)p)[i] = v;
  else     ((__hip_bfloat16*)p)[i] = __float2bfloat16(v);
}
// bf16 pair (u32) -> two floats via bit ops (no cvt instruction)
__device__ __forceinline__ float blo(unsigned u) {
  union { unsigned u; float f; } c; c.u = u << 16; return c.f;
}
__device__ __forceinline__ float bhi(unsigned u) {
  union { unsigned u; float f; } c; c.u = u & 0xffff0000u; return c.f;
}

// ---- dtype detection (device-side, graph-safe) ------------------------------
__global__ void detect_kernel(const unsigned short* __restrict__ x,
                              const int* __restrict__ ei, int* __restrict__ flags) {
  int t = threadIdx.x;
  unsigned short u = x[t];
  int ex = (u >> 7) & 0xFF;
  if (ex >= 0xC0) atomicOr(&flags[0], 1);          // fp32 viewed as bf16 -> wild exps
  if (t < 128 && ei[2 * t + 1] != 0) atomicOr(&flags[1], 1);  // nonzero -> int32
}

// ---- pack all 4 weight matrices in ONE launch -------------------------------
// W [K,N] row-major -> MFMA B-fragment layout (bf16)
__global__ __launch_bounds__(64) void pack_all(const void* __restrict__ W1,
                                               const void* __restrict__ W2,
                                               const void* __restrict__ G1,
                                               const void* __restrict__ G2,
                                               __hip_bfloat16* __restrict__ P1,
                                               __hip_bfloat16* __restrict__ P2,
                                               __hip_bfloat16* __restrict__ PG1,
                                               __hip_bfloat16* __restrict__ PG2,
                                               const int* __restrict__ flags) {
  int f32 = flags[0] != 0;
  int b = blockIdx.x;
  const void* W; __hip_bfloat16* P; int KS, N, ks, ct;
  if (b < 64)      { W = W1; P = P1;  KS = 8; N = 128; int c = b;      ks = c & 7; ct = c >> 3; }
  else if (b < 80) { W = W2; P = P2;  KS = 4; N = 64;  int c = b - 64; ks = c & 3; ct = c >> 2; }
  else if (b < 88) { W = G1; P = PG1; KS = 2; N = 64;  int c = b - 80; ks = c & 1; ct = c >> 1; }
  else             { W = G2; P = PG2; KS = 2; N = 64;  int c = b - 88; ks = c & 1; ct = c >> 1; }
  int lane = threadIdx.x;
  int g = lane >> 4, m = lane & 15;
  size_t base = ((size_t)(ct * KS + ks) * 64 + (size_t)lane) * 8;
#pragma unroll
  for (int j = 0; j < 8; ++j)
    P[base + j] = __float2bfloat16(
        loadF(W, (size_t)(ks * 32 + g * 8 + j) * N + (size_t)(ct * 16 + m), f32));
}

// ---- FUSED MLP: h2 = lk(lk(x@W1+b1)@W2+b2), one 32-row tile per block -------
// Stage x tile (16KB, XOR-swizzled bf16) -> MFMA K=256 N=128 -> h1 tile to
// LDS (8KB, same swizzle) -> MFMA K=128 N=64 -> h2 global. Saves the 25.6MB
// h1 write + read and one dispatch. Numerics identical (same bf16 round point).
__global__ __launch_bounds__(256) void gemm_fused12(const void* __restrict__ A,
                                                    const __hip_bfloat16* __restrict__ Bp1,
                                                    const void* __restrict__ b1,
                                                    const __hip_bfloat16* __restrict__ Bp2,
                                                    const void* __restrict__ b2,
                                                    __hip_bfloat16* __restrict__ Out,
                                                    int M, const int* __restrict__ flags) {
  constexpr int K1 = 256, CPR1 = K1 / 8;      // 32 chunks per x-row
  __shared__ char xtile[32 * K1 * 2];         // 16 KB
  __shared__ char h1t[32 * 128 * 2];          // 8 KB
  int f32 = flags[0] != 0;
  int tid = threadIdx.x;
  int lane = tid & 63;
  int w = tid >> 6;
  int m = lane & 15, g = lane >> 4;
  int row0 = blockIdx.x << 5;

  // ---- stage x ----
  if (f32) {
    constexpr int PP = K1 / 64;               // 4 chunk-pairs per thread
    float4 sr[2 * PP];
#pragma unroll
    for (int j = 0; j < PP; ++j) {
      int q = j * 256 + tid;
      int r = q / CPR1, pc = q - r * CPR1;
      int gr = row0 + r; if (gr >= M) gr = M - 1;
      const float* src = (const float*)A + (size_t)gr * K1 + (size_t)pc * 8;
      sr[2 * j]     = *(const float4*)src;
      sr[2 * j + 1] = *(const float4*)(src + 4);
    }
#pragma unroll
    for (int j = 0; j < PP; ++j) {
      int q = j * 256 + tid;
      int r = q / CPR1, pc = q - r * CPR1;
      bf16x8 ov;
      ov[0] = f2b(sr[2 * j].x);     ov[1] = f2b(sr[2 * j].y);
      ov[2] = f2b(sr[2 * j].z);     ov[3] = f2b(sr[2 * j].w);
      ov[4] = f2b(sr[2 * j + 1].x); ov[5] = f2b(sr[2 * j + 1].y);
      ov[6] = f2b(sr[2 * j + 1].z); ov[7] = f2b(sr[2 * j + 1].w);
      *(bf16x8*)(xtile + (size_t)r * (K1 * 2) + (size_t)((pc ^ (r & 7)) * 16)) = ov;
    }
  } else {
    constexpr int PERW = 32 * CPR1 / 4;
#pragma unroll
    for (int i = 0; i < PERW; i += 64) {
      int p = w * PERW + i + lane;
      int r = p / CPR1, pc = p - r * CPR1;
      int gr = row0 + r; if (gr >= M) gr = M - 1;
      const char* src = (const char*)A + (size_t)gr * (K1 * 2) +
                        (size_t)((pc ^ (r & 7)) * 16);
      char* dst = xtile + (size_t)(w * PERW + i) * 16;
      __builtin_amdgcn_global_load_lds(
          (const __attribute__((address_space(1))) void*)src,
          (__attribute__((address_space(3))) void*)dst, 16, 0, 0);
    }
  }
  __syncthreads();

  // ---- GEMM 1: K=256, N=128 (4 waves x CT=2) ----
  {
    const __hip_bfloat16* bbase = Bp1 + ((size_t)(w * 2) * 8 * 64 + (size_t)lane) * 8;
    f32x4 accs[2][2];
#pragma unroll
    for (int tt = 0; tt < 2; ++tt)
#pragma unroll
      for (int cc = 0; cc < 2; ++cc) accs[tt][cc] = (f32x4){0, 0, 0, 0};
#pragma unroll
    for (int ks = 0; ks < 8; ++ks) {
      bf16x8 a[2];
#pragma unroll
      for (int tt = 0; tt < 2; ++tt) {
        int r = tt * 16 + m;
        int c = ks * 4 + g;
        a[tt] = *(const bf16x8*)(xtile + (size_t)r * (K1 * 2) +
                                 (size_t)((c ^ (r & 7)) * 16));
      }
      const __hip_bfloat16* bb = bbase + (size_t)ks * 64 * 8;
#pragma unroll
      for (int cc = 0; cc < 2; ++cc) {
        bf16x8 b = *(const bf16x8*)(bb + (size_t)cc * 8 * 64 * 8);
#pragma unroll
        for (int tt = 0; tt < 2; ++tt)
          accs[tt][cc] = __builtin_amdgcn_mfma_f32_16x16x32_bf16(a[tt], b, accs[tt][cc], 0, 0, 0);
      }
    }
    // epilogue 1 -> h1 tile in LDS (bf16, chunk-XOR swizzle)
    float bv[2];
#pragma unroll
    for (int cc = 0; cc < 2; ++cc)
      bv[cc] = loadF(b1, (size_t)((w * 2 + cc) * 16 + m), f32);
#pragma unroll
    for (int tt = 0; tt < 2; ++tt) {
#pragma unroll
      for (int r = 0; r < 4; ++r) {
        int row = tt * 16 + g * 4 + r;
#pragma unroll
        for (int cc = 0; cc < 2; ++cc) {
          float v = lk(accs[tt][cc][r] + bv[cc]);
          int colb = ((w * 2 + cc) * 16 + m) * 2;     // byte within row
          int ch = colb >> 4, off = colb & 15;
          *(__hip_bfloat16*)(h1t + (size_t)row * 256 +
                             (size_t)((ch ^ (row & 7)) * 16) + off) =
              __float2bfloat16(v);
        }
      }
    }
  }
  __syncthreads();

  // ---- GEMM 2: K=128, N=64 (4 waves x CT=1) ----
  {
    const __hip_bfloat16* bbase = Bp2 + ((size_t)w * 4 * 64 + (size_t)lane) * 8;
    f32x4 accs[2];
    accs[0] = (f32x4){0, 0, 0, 0};
    accs[1] = (f32x4){0, 0, 0, 0};
#pragma unroll
    for (int ks = 0; ks < 4; ++ks) {
      bf16x8 a[2];
#pragma unroll
      for (int tt = 0; tt < 2; ++tt) {
        int r = tt * 16 + m;
        int c = ks * 4 + g;
        a[tt] = *(const bf16x8*)(h1t + (size_t)r * 256 +
                                 (size_t)((c ^ (r & 7)) * 16));
      }
      const __hip_bfloat16* bb = bbase + (size_t)ks * 64 * 8;
      bf16x8 b = *(const bf16x8*)bb;
#pragma unroll
      for (int tt = 0; tt < 2; ++tt)
        accs[tt] = __builtin_amdgcn_mfma_f32_16x16x32_bf16(a[tt], b, accs[tt], 0, 0, 0);
    }
    float bv = loadF(b2, (size_t)(w * 16 + m), f32);
#pragma unroll
    for (int tt = 0; tt < 2; ++tt) {
#pragma unroll
      for (int r = 0; r < 4; ++r) {
        int ro = row0 + tt * 16 + g * 4 + r;
        if (ro < M) {
          int col = w * 16 + m;
          Out[(size_t)ro * 64 + col] = __float2bfloat16(lk(accs[tt][r] + bv));
        }
      }
    }
  }
}

// ---- tiled GEMM (bf16 A): one 32-row tile per block, XOR-swizzled LDS -------
template <int KS, int CT>
__global__ __launch_bounds__(256) void gemm_bt(const void* __restrict__ A,
                                               const __hip_bfloat16* __restrict__ Bp,
                                               const void* __restrict__ bias,
                                               void* __restrict__ Out, int out_bf16,
                                               __hip_bfloat16* __restrict__ Yout,
                                               const float* __restrict__ dinv,
                                               int M, int N, int act,
                                               const int* __restrict__ flags) {
  constexpr int K = KS * 32;
  constexpr int CPR = K / 8;            // bf16 16B chunks per row
  __shared__ char tile[32 * K * 2];
  int tid = threadIdx.x;
  int lane = tid & 63;
  int w = tid >> 6;                     // wave id = col partition
  int m = lane & 15, g = lane >> 4;
  int row0 = blockIdx.x << 5;

  {                                     // bf16 input: async global->LDS
    constexpr int PERW = 32 * CPR / 4;  // chunks per wave
#pragma unroll
    for (int i = 0; i < PERW; i += 64) {
      int p = w * PERW + i + lane;
      int r = p / CPR, pc = p - r * CPR;
      int gr = row0 + r; if (gr >= M) gr = M - 1;
      const char* src = (const char*)A + (size_t)gr * (K * 2) +
                        (size_t)((pc ^ (r & 7)) * 16);
      char* dst = tile + (size_t)(w * PERW + i) * 16;   // wave-uniform base
      __builtin_amdgcn_global_load_lds(
          (const __attribute__((address_space(1))) void*)src,
          (__attribute__((address_space(3))) void*)dst, 16, 0, 0);
    }
  }
  __syncthreads();

  const __hip_bfloat16* bbase = Bp + ((size_t)(w * CT) * KS * 64 + (size_t)lane) * 8;
  f32x4 accs[2][CT];
#pragma unroll
  for (int tt = 0; tt < 2; ++tt)
#pragma unroll
    for (int cc = 0; cc < CT; ++cc) accs[tt][cc] = (f32x4){0, 0, 0, 0};

#pragma unroll
  for (int ks = 0; ks < KS; ++ks) {
    bf16x8 a[2];
#pragma unroll
    for (int tt = 0; tt < 2; ++tt) {
      int r = tt * 16 + m;
      int c = ks * 4 + g;
      a[tt] = *(const bf16x8*)(tile + (size_t)r * (K * 2) +
                               (size_t)((c ^ (r & 7)) * 16));
    }
    const __hip_bfloat16* bb = bbase + (size_t)ks * 64 * 8;
#pragma unroll
    for (int cc = 0; cc < CT; ++cc) {
      bf16x8 b = *(const bf16x8*)(bb + (size_t)cc * KS * 64 * 8);
#pragma unroll
      for (int tt = 0; tt < 2; ++tt)
        accs[tt][cc] = __builtin_amdgcn_mfma_f32_16x16x32_bf16(a[tt], b, accs[tt][cc], 0, 0, 0);
    }
  }

  // epilogue
  int f32 = flags[0] != 0;
  float bv[CT];
#pragma unroll
  for (int cc = 0; cc < CT; ++cc)
    bv[cc] = bias ? loadF(bias, (size_t)((w * CT + cc) * 16 + m), f32) : 0.f;
#pragma unroll
  for (int tt = 0; tt < 2; ++tt) {
#pragma unroll
    for (int r = 0; r < 4; ++r) {
      int ro = row0 + tt * 16 + g * 4 + r;
      if (ro < M) {
        float di = Yout ? dinv[ro] : 0.f;
#pragma unroll
        for (int cc = 0; cc < CT; ++cc) {
          int col = (w * CT + cc) * 16 + m;
          float v = accs[tt][cc][r] + bv[cc];
          if (act) v = lk(v);
          if (Out) {
            if (out_bf16) ((__hip_bfloat16*)Out)[(size_t)ro * N + col] = __float2bfloat16(v);
            else          ((float*)Out)[(size_t)ro * N + col] = v;
          }
          if (Yout) Yout[(size_t)ro * N + col] = __float2bfloat16(v * di);
        }
      }
    }
  }
}

// ---- CSR build pass A: LDS-staged binning, batched stream flush -------------
// LDS: bcnt[NB] | gbase[NB] | bins[NB*LCAP] (int2)
__global__ __launch_bounds__(256) void bin_kernel(const int* __restrict__ ei,
                                                  int* __restrict__ cur,
                                                  int2* __restrict__ rec,
                                                  int E, int NB,
                                                  const int* __restrict__ flags) {
  extern __shared__ int lds[];
  int* bcnt = lds;
  int* gbase = lds + NB;
  int2* bins = (int2*)(lds + 2 * NB);
  int i64 = flags[1] == 0;
  // real XCD id (hwreg 20); any value is correctness-safe after &7
  int stripe = __builtin_amdgcn_s_getreg(63508) & (NSTR - 1);
  int t = threadIdx.x;
  const int perRound = 256 * KEDGE;
  for (int base = blockIdx.x * perRound; base < E; base += gridDim.x * perRound) {
    for (int b = t; b < NB; b += 256) bcnt[b] = 0;
    __syncthreads();
    // bin into LDS
#pragma unroll 1
    for (int k = 0; k < KEDGE; ++k) {
      int i = base + k * 256 + t;
      if (i < E) {
        int r, c;
        if (i64) {
          r = ((const int2*)ei)[i].x;            // int64 low word
          c = ((const int2*)ei)[(size_t)E + i].x;
        } else {
          r = ei[i];
          c = ei[(size_t)E + i];
        }
        int b = c >> BSHIFT;
        int pos = atomicAdd(&bcnt[b], 1);
        if (pos < LCAP) {
          bins[b * LCAP + pos] = make_int2(r, c);
        } else {                                   // rare overflow: direct append
          int bs = b * NSTR + stripe;
          int slot = atomicAdd(&cur[bs], 1);
          if (slot < BCAP) rec[(size_t)bs * BCAP + slot] = make_int2(r, c);
        }
      }
    }
    __syncthreads();
    // reserve stream ranges (parallel atomics, no serialized chain)
    for (int b = t; b < NB; b += 256) {
      int n = min(bcnt[b], LCAP);
      if (n > 0) gbase[b] = atomicAdd(&cur[b * NSTR + stripe], n);
    }
    __syncthreads();
    // contiguous copy LDS -> stream
    int lane = t & 63, w = t >> 6;
    for (int b = w; b < NB; b += 4) {
      int n = min(bcnt[b], LCAP);
      if (n == 0) continue;
      int gb = gbase[b];
      size_t sb = (size_t)(b * NSTR + stripe) * BCAP;
      if (lane < n && gb + lane < BCAP)
        rec[sb + gb + lane] = bins[b * LCAP + lane];
    }
    __syncthreads();
  }
}

// Pass B: one block per bucket, 512 threads. Inline global prefix: base_b =
// sum_{i < b*NSTR} min(cur[i],BCAP) from the L2-hot cur array + LDS reduce.
__global__ __launch_bounds__(512) void place_kernel(const int2* __restrict__ rec,
                                                    const int* __restrict__ cur,
                                                    int* __restrict__ rowptr,
                                                    int* __restrict__ csr,
                                                    float* __restrict__ dinv, int Nn) {
  int b = blockIdx.x;
  int lo = b << BSHIFT;
  int t = threadIdx.x;
  __shared__ int cnt[BW];
  __shared__ int sc[BW];
  __shared__ int cursor[BW];
  __shared__ int red[512];
  int part = 0;
  for (int i = t; i < b * NSTR; i += 512) part += min(cur[i], BCAP);
  red[t] = part;
  if (t < BW) cnt[t] = 0;
  __syncthreads();
  for (int o = 256; o > 0; o >>= 1) {
    if (t < o) red[t] += red[t + o];
    __syncthreads();
  }
  int base = red[0];                    // global segment base for this bucket
#pragma unroll 1
  for (int s = 0; s < NSTR; ++s) {
    int n = min(cur[b * NSTR + s], BCAP);
    const int2* rp = rec + (size_t)(b * NSTR + s) * BCAP;
    for (int j = t; j < n; j += 512) atomicAdd(&cnt[rp[j].y - lo], 1);
  }
  __syncthreads();
  int v = 0;
  if (t < BW) { v = cnt[t]; sc[t] = v; }
  __syncthreads();
  for (int o = 1; o < BW; o <<= 1) {
    int a = (t >= o && t < BW) ? sc[t - o] : 0;
    __syncthreads();
    if (t < BW) sc[t] += a;
    __syncthreads();
  }
  if (t < BW) {
    int col = lo + t;
    if (col < Nn) {
      rowptr[col] = base + sc[t];               // segment END
      dinv[col] = rsqrtf((float)v + 1.0f);
    }
    cursor[t] = base + sc[t] - v;               // segment start
  }
  __syncthreads();
#pragma unroll 1
  for (int s = 0; s < NSTR; ++s) {
    int n = min(cur[b * NSTR + s], BCAP);
    const int2* rp = rec + (size_t)(b * NSTR + s) * BCAP;
    for (int j = t; j < n; j += 512) {
      int2 e = rp[j];
      int pos = atomicAdd(&cursor[e.y - lo], 1);
      csr[pos] = e.x;
    }
  }
}

// ---- pull-mode aggregation + self-term + bias + leaky, fused ----------------
// Half-wave (32 lanes) per node; coalesced csr window load + shfl broadcast
// (shfl beats per-lane broadcast loads: keeps csr off the address critical
// path -- round 8 regression). Self term uses y[node]*di == xw*di*di.
// Optionally reduces edge-head scores ssrc[n]=h[n].wp1, sdst[n]=h[n].wp2.
__global__ __launch_bounds__(256) void gather_kernel(const __hip_bfloat16* __restrict__ y,
                                                     const int* __restrict__ csr,
                                                     const int* __restrict__ rowptr,
                                                     const float* __restrict__ dinv,
                                                     const void* __restrict__ bias,
                                                     void* __restrict__ outp, size_t obase,
                                                     int out_use_flag, int Nn,
                                                     float* __restrict__ ssrc,
                                                     float* __restrict__ sdst,
                                                     const void* __restrict__ Wp,
                                                     const int* __restrict__ flags) {
  int f32 = flags[0] != 0;
  int of32 = out_use_flag ? f32 : 0;    // intermediate h3 stored bf16
  int lane = threadIdx.x & 63;
  int w = (blockIdx.x * blockDim.x + threadIdx.x) >> 6;
  if (2 * w >= Nn) return;
  int half = lane >> 5;                 // which node of the pair
  int hl = lane & 31;                   // feature-pair index (f = 2*hl)
  int hb = half << 5;                   // shfl base for this half
  int node = 2 * w + half;
  int alive = node < Nn;
  int nd = alive ? node : Nn - 1;       // clamp for safe loads
  int s = (nd == 0) ? 0 : rowptr[nd - 1];
  int e = rowptr[nd];
  if (!alive) e = s;
  const unsigned* yu = (const unsigned*)y;    // row = 32 bf16-pairs
  float p0a = 0, p1a = 0, p0b = 0, p1b = 0;
  float p0c = 0, p1c = 0, p0d = 0, p1d = 0;
  for (int base = s; base < e; base += 32) {
    int cnt = e - base; if (cnt > 32) cnt = 32;
    int rl = (base + hl < e) ? csr[base + hl] : 0;
    int j = 0;
    for (; j + 8 <= cnt; j += 8) {
      int r0 = __shfl(rl, hb + j + 0, 64);
      int r1 = __shfl(rl, hb + j + 1, 64);
      int r2 = __shfl(rl, hb + j + 2, 64);
      int r3 = __shfl(rl, hb + j + 3, 64);
      int r4 = __shfl(rl, hb + j + 4, 64);
      int r5 = __shfl(rl, hb + j + 5, 64);
      int r6 = __shfl(rl, hb + j + 6, 64);
      int r7 = __shfl(rl, hb + j + 7, 64);
      unsigned u0 = yu[(unsigned)r0 * 32u + hl];
      unsigned u1 = yu[(unsigned)r1 * 32u + hl];
      unsigned u2 = yu[(unsigned)r2 * 32u + hl];
      unsigned u3 = yu[(unsigned)r3 * 32u + hl];
      unsigned u4 = yu[(unsigned)r4 * 32u + hl];
      unsigned u5 = yu[(unsigned)r5 * 32u + hl];
      unsigned u6 = yu[(unsigned)r6 * 32u + hl];
      unsigned u7 = yu[(unsigned)r7 * 32u + hl];
      p0a += blo(u0); p1a += bhi(u0);
      p0b += blo(u1); p1b += bhi(u1);
      p0c += blo(u2); p1c += bhi(u2);
      p0d += blo(u3); p1d += bhi(u3);
      p0a += blo(u4); p1a += bhi(u4);
      p0b += blo(u5); p1b += bhi(u5);
      p0c += blo(u6); p1c += bhi(u6);
      p0d += blo(u7); p1d += bhi(u7);
    }
    for (; j + 4 <= cnt; j += 4) {
      int r0 = __shfl(rl, hb + j + 0, 64);
      int r1 = __shfl(rl, hb + j + 1, 64);
      int r2 = __shfl(rl, hb + j + 2, 64);
      int r3 = __shfl(rl, hb + j + 3, 64);
      unsigned u0 = yu[(unsigned)r0 * 32u + hl];
      unsigned u1 = yu[(unsigned)r1 * 32u + hl];
      unsigned u2 = yu[(unsigned)r2 * 32u + hl];
      unsigned u3 = yu[(unsigned)r3 * 32u + hl];
      p0a += blo(u0); p1a += bhi(u0);
      p0b += blo(u1); p1b += bhi(u1);
      p0c += blo(u2); p1c += bhi(u2);
      p0d += blo(u3); p1d += bhi(u3);
    }
    for (; j < cnt; ++j) {
      int r0 = __shfl(rl, hb + j, 64);
      unsigned u0 = yu[(unsigned)r0 * 32u + hl];
      p0a += blo(u0); p1a += bhi(u0);
    }
  }
  float acc0 = (p0a + p0b) + (p0c + p0d);
  float acc1 = (p1a + p1b) + (p1c + p1d);
  unsigned un = yu[(unsigned)nd * 32u + hl];   // self term: y[node]*di
  acc0 += blo(un); acc1 += bhi(un);
  float di = dinv[nd];
  int f = hl * 2;
  float v0 = lk(di * acc0 + loadF(bias, (size_t)f, f32));
  float v1 = lk(di * acc1 + loadF(bias, (size_t)(f + 1), f32));
  if (alive) {
    if (of32) {
      *(float2*)((float*)outp + obase + (size_t)node * 64 + f) = make_float2(v0, v1);
    } else {
      union { unsigned u; unsigned short ss[2]; } pk;
      pk.ss[0] = (unsigned short)f2b(v0);
      pk.ss[1] = (unsigned short)f2b(v1);
      *(unsigned*)((__hip_bfloat16*)outp + obase + (size_t)node * 64 + f) = pk.u;
    }
  }
  if (ssrc) {
    float q1 = v0 * loadF(Wp, (size_t)f, f32) + v1 * loadF(Wp, (size_t)(f + 1), f32);
    float q2 = v0 * loadF(Wp, (size_t)(64 + f), f32) + v1 * loadF(Wp, (size_t)(65 + f), f32);
#pragma unroll
    for (int o = 16; o > 0; o >>= 1) {        // reduce within each 32-lane half
      q1 += __shfl_down(q1, o, 64);
      q2 += __shfl_down(q2, o, 64);
    }
    if (hl == 0 && alive) { ssrc[node] = q1; sdst[node] = q2; }
  }
}

// ---- edge scoring head: one THREAD per edge, scores precomputed -------------
__global__ __launch_bounds__(256) void edge_head_kernel(void* __restrict__ dout,
                                                        const int* __restrict__ eli,
                                                        const void* __restrict__ ea,
                                                        const float* __restrict__ ssrc,
                                                        const float* __restrict__ sdst,
                                                        const void* __restrict__ Wp,
                                                        const void* __restrict__ bp,
                                                        int EL, const int* __restrict__ flags) {
  int f32 = flags[0] != 0;
  int i64 = flags[1] == 0;
  int tid = blockIdx.x * blockDim.x + threadIdx.x;
  if (tid >= EL) return;
  int s, d;
  if (i64) {
    s = ((const int2*)eli)[tid].x;              // int64 low word, single 8B load
    d = ((const int2*)eli)[(size_t)EL + tid].x;
  } else {
    s = eli[tid];
    d = eli[(size_t)EL + tid];
  }
  float acc = ssrc[s] + sdst[d] + loadF(bp, 0, f32);
  if (f32) {
    const float* eap = (const float*)ea + (size_t)tid * 8;
    float4 u0 = *(const float4*)eap;
    float4 u1 = *(const float4*)(eap + 4);
    acc += u0.x * loadF(Wp, 128, 1) + u0.y * loadF(Wp, 129, 1) +
           u0.z * loadF(Wp, 130, 1) + u0.w * loadF(Wp, 131, 1) +
           u1.x * loadF(Wp, 132, 1) + u1.y * loadF(Wp, 133, 1) +
           u1.z * loadF(Wp, 134, 1) + u1.w * loadF(Wp, 135, 1);
  } else {
    bf16x8 u = *(const bf16x8*)((const __hip_bfloat16*)ea + (size_t)tid * 8);
#pragma unroll
    for (int j = 0; j < 8; ++j) {
      union { short s; __hip_bfloat16 h; } cv; cv.s = u[j];
      acc += __bfloat162float(cv.h) * loadF(Wp, (size_t)(128 + j), 0);
    }
  }
  storeF(dout, (size_t)tid, f32, acc);
}

extern "C" void kernel_launch(void* const* d_in, const int* in_sizes, int n_in,
                              void* d_out, int out_size, void* d_ws, size_t ws_size,
                              hipStream_t stream) {
  const void* x   = d_in[0];
  const int* ei   = (const int*)d_in[1];
  const int* eli  = (const int*)d_in[2];
  const void* ea  = d_in[3];
  const void* W1  = d_in[4];
  const void* b1  = d_in[5];
  const void* W2  = d_in[6];
  const void* b2  = d_in[7];
  const void* Wg1 = d_in[8];
  const void* bg1 = d_in[9];
  const void* Wg2 = d_in[10];
  const void* bg2 = d_in[11];
  const void* Wp  = d_in[12];
  const void* bp  = d_in[13];

  const int Nn = in_sizes[0] / 256;
  const int E  = in_sizes[1] / 2;
  const int EL = in_sizes[2] / 2;
  const int NB = (Nn + BW - 1) >> BSHIFT;       // col buckets

  char* ws = (char*)d_ws;
  size_t off = 0;
  auto take = [&](size_t bytes) -> char* {
    char* p = ws + off;
    off = (off + bytes + 255) & ~(size_t)255;
    return p;
  };
  int*   flags  = (int*)take(256);
  int*   cur    = (int*)take((size_t)NB * NSTR * 4);   // contiguous after flags
  int*   rowptr = (int*)take((size_t)Nn * 4);
  float* dinv   = (float*)take((size_t)Nn * 4);
  float* ssrc   = (float*)take((size_t)Nn * 4);
  float* sdst   = (float*)take((size_t)Nn * 4);
  int*   csr    = (int*)take((size_t)E * 4);
  int2*  rec    = (int2*)take((size_t)NB * NSTR * BCAP * 8);
  __hip_bfloat16* pW1 = (__hip_bfloat16*)take(256 * 128 * 2);
  __hip_bfloat16* pW2 = (__hip_bfloat16*)take(128 * 64 * 2);
  __hip_bfloat16* pG1 = (__hip_bfloat16*)take(64 * 64 * 2);
  __hip_bfloat16* pG2 = (__hip_bfloat16*)take(64 * 64 * 2);
  char* regionA = take((size_t)Nn * 128 * 4);   // y(bf16) at +Nn*256B
  char* regionB = take((size_t)Nn * 64 * 4);    // h2(bf16) | later h3(bf16)
  __hip_bfloat16* y = (__hip_bfloat16*)(regionA + (size_t)Nn * 64 * 4);
  __hip_bfloat16* h2 = (__hip_bfloat16*)regionB;
  __hip_bfloat16* h3 = (__hip_bfloat16*)regionB;

  // flags + cur are contiguous -> one memset covers both
  hipMemsetAsync(flags, 0, 256 + (((size_t)NB * NSTR * 4 + 255) & ~(size_t)255), stream);
  detect_kernel<<<1, 256, 0, stream>>>((const unsigned short*)x, ei, flags);

  pack_all<<<96, 64, 0, stream>>>(W1, W2, Wg1, Wg2, pW1, pW2, pG1, pG2, flags);

  // CSR build: LDS-staged binning -> place (scan fused into place)
  const int ldsbytes = NB * (8 + LCAP * 8);     // bcnt + gbase + bins
  const int nbin = (E + 256 * KEDGE - 1) / (256 * KEDGE);
  bin_kernel<<<nbin, 256, ldsbytes, stream>>>(ei, cur, rec, E, NB, flags);
  place_kernel<<<NB, 512, 0, stream>>>(rec, cur, rowptr, csr, dinv, Nn);

  // fused MLP (gemm1+gemm2): x -> h2, one dispatch
  const int tblocks = (Nn + 31) / 32;
  gemm_fused12<<<tblocks, 256, 0, stream>>>(x, pW1, b1, pW2, b2, h2, Nn, flags);

  // gathers: 2 nodes per wave (half-wave per node)
  const int gwaves = (Nn + 1) / 2;
  const int gblocks = (gwaves + 3) / 4;
  gemm_bt<2, 1><<<tblocks, 256, 0, stream>>>(h2, pG1, nullptr, nullptr, 0, y, dinv,
                                             Nn, 64, 0, flags);
  gather_kernel<<<gblocks, 256, 0, stream>>>(y, csr, rowptr, dinv, bg1,
                                             h3, 0, 0, Nn,
                                             nullptr, nullptr, nullptr, flags);

  gemm_bt<2, 1><<<tblocks, 256, 0, stream>>>(h3, pG2, nullptr, nullptr, 0, y, dinv,
                                             Nn, 64, 0, flags);
  gather_kernel<<<gblocks, 256, 0, stream>>>(y, csr, rowptr, dinv, bg2,
                                             d_out, (size_t)EL, 1, Nn,
                                             ssrc, sdst, Wp, flags);

  edge_head_kernel<<<(EL + 255) / 256, 256, 0, stream>>>(d_out, eli, ea, ssrc, sdst,
                                                         Wp, bp, EL, flags);
}

// Round 10
// 341.972 us; speedup vs baseline: 1.1160x; 1.0573x over previous
//
#include <hip/hip_runtime.h>
#include <hip/hip_bf16.h>

typedef __attribute__((ext_vector_type(8))) short bf16x8;
typedef __attribute__((ext_vector_type(4))) float f32x4;

#define BSHIFT 8          // cols per bucket = 256
#define BW 256
#define NSTR 8            // stripes (XCDs)
#define BCAP 768          // records per (bucket,stripe) stream; mean ~511
#define LCAP 24           // LDS records per bucket per round
#define KEDGE 16          // edges per thread per round (4096/block-round)

__device__ __forceinline__ float lk(float v) { return v > 0.f ? v : 0.01f * v; }

__device__ __forceinline__ short f2b(float v) {
  union { __hip_bfloat16 h; short s; } u;
  u.h = __float2bfloat16(v);
  return u.s;
}
__device__ __forceinline__ float loadF(const void* p, size_t i, int f32) {
  return f32 ? ((const float*)p)[i]
             : __bfloat162float(((const __hip_bfloat16*)p)[i]);
}
__device__ __forceinline__ void storeF(void* p, size_t i, int f32, float v) {
  if (f32) ((float*)p)[i] = v;
  else     ((__hip_bfloat16*)p)[i] = __float2bfloat16(v);
}
// bf16 pair (u32) -> two floats via bit ops (no cvt instruction)
__device__ __forceinline__ float blo(unsigned u) {
  union { unsigned u; float f; } c; c.u = u << 16; return c.f;
}
__device__ __forceinline__ float bhi(unsigned u) {
  union { unsigned u; float f; } c; c.u = u & 0xffff0000u; return c.f;
}

// ---- dtype detection (device-side, graph-safe) ------------------------------
__global__ void detect_kernel(const unsigned short* __restrict__ x,
                              const int* __restrict__ ei, int* __restrict__ flags) {
  int t = threadIdx.x;
  unsigned short u = x[t];
  int ex = (u >> 7) & 0xFF;
  if (ex >= 0xC0) atomicOr(&flags[0], 1);          // fp32 viewed as bf16 -> wild exps
  if (t < 128 && ei[2 * t + 1] != 0) atomicOr(&flags[1], 1);  // nonzero -> int32
}

// ---- pack all 4 weight matrices in ONE launch -------------------------------
// W [K,N] row-major -> MFMA B-fragment layout (bf16)
__global__ __launch_bounds__(64) void pack_all(const void* __restrict__ W1,
                                               const void* __restrict__ W2,
                                               const void* __restrict__ G1,
                                               const void* __restrict__ G2,
                                               __hip_bfloat16* __restrict__ P1,
                                               __hip_bfloat16* __restrict__ P2,
                                               __hip_bfloat16* __restrict__ PG1,
                                               __hip_bfloat16* __restrict__ PG2,
                                               const int* __restrict__ flags) {
  int f32 = flags[0] != 0;
  int b = blockIdx.x;
  const void* W; __hip_bfloat16* P; int KS, N, ks, ct;
  if (b < 64)      { W = W1; P = P1;  KS = 8; N = 128; int c = b;      ks = c & 7; ct = c >> 3; }
  else if (b < 80) { W = W2; P = P2;  KS = 4; N = 64;  int c = b - 64; ks = c & 3; ct = c >> 2; }
  else if (b < 88) { W = G1; P = PG1; KS = 2; N = 64;  int c = b - 80; ks = c & 1; ct = c >> 1; }
  else             { W = G2; P = PG2; KS = 2; N = 64;  int c = b - 88; ks = c & 1; ct = c >> 1; }
  int lane = threadIdx.x;
  int g = lane >> 4, m = lane & 15;
  size_t base = ((size_t)(ct * KS + ks) * 64 + (size_t)lane) * 8;
#pragma unroll
  for (int j = 0; j < 8; ++j)
    P[base + j] = __float2bfloat16(
        loadF(W, (size_t)(ks * 32 + g * 8 + j) * N + (size_t)(ct * 16 + m), f32));
}

// ---- FUSED MLP + GCN1 premul: y = bf16(lk(lk(x@W1+b1)@W2+b2) @ G1 * dinv) ---
// One 32-row tile per block. x tile (16KB) -> MFMA K=256 N=128 -> h1 LDS (8KB)
// -> MFMA K=128 N=64 -> h2 LDS (4KB) -> MFMA K=64 N=64 -> y global. h1/h2
// never touch HBM. All LDS tiles use the chunk-XOR swizzle (chunk ^= row&7).
__global__ __launch_bounds__(256) void gemm_fused123(const void* __restrict__ A,
                                                     const __hip_bfloat16* __restrict__ Bp1,
                                                     const void* __restrict__ b1,
                                                     const __hip_bfloat16* __restrict__ Bp2,
                                                     const void* __restrict__ b2,
                                                     const __hip_bfloat16* __restrict__ BpG,
                                                     const float* __restrict__ dinv,
                                                     __hip_bfloat16* __restrict__ Yout,
                                                     int M, const int* __restrict__ flags) {
  constexpr int K1 = 256, CPR1 = K1 / 8;      // 32 chunks per x-row
  __shared__ char xtile[32 * K1 * 2];         // 16 KB
  __shared__ char h1t[32 * 128 * 2];          // 8 KB
  __shared__ char h2t[32 * 64 * 2];           // 4 KB
  int f32 = flags[0] != 0;
  int tid = threadIdx.x;
  int lane = tid & 63;
  int w = tid >> 6;
  int m = lane & 15, g = lane >> 4;
  int row0 = blockIdx.x << 5;

  // ---- stage x ----
  if (f32) {
    constexpr int PP = K1 / 64;               // 4 chunk-pairs per thread
    float4 sr[2 * PP];
#pragma unroll
    for (int j = 0; j < PP; ++j) {
      int q = j * 256 + tid;
      int r = q / CPR1, pc = q - r * CPR1;
      int gr = row0 + r; if (gr >= M) gr = M - 1;
      const float* src = (const float*)A + (size_t)gr * K1 + (size_t)pc * 8;
      sr[2 * j]     = *(const float4*)src;
      sr[2 * j + 1] = *(const float4*)(src + 4);
    }
#pragma unroll
    for (int j = 0; j < PP; ++j) {
      int q = j * 256 + tid;
      int r = q / CPR1, pc = q - r * CPR1;
      bf16x8 ov;
      ov[0] = f2b(sr[2 * j].x);     ov[1] = f2b(sr[2 * j].y);
      ov[2] = f2b(sr[2 * j].z);     ov[3] = f2b(sr[2 * j].w);
      ov[4] = f2b(sr[2 * j + 1].x); ov[5] = f2b(sr[2 * j + 1].y);
      ov[6] = f2b(sr[2 * j + 1].z); ov[7] = f2b(sr[2 * j + 1].w);
      *(bf16x8*)(xtile + (size_t)r * (K1 * 2) + (size_t)((pc ^ (r & 7)) * 16)) = ov;
    }
  } else {
    constexpr int PERW = 32 * CPR1 / 4;
#pragma unroll
    for (int i = 0; i < PERW; i += 64) {
      int p = w * PERW + i + lane;
      int r = p / CPR1, pc = p - r * CPR1;
      int gr = row0 + r; if (gr >= M) gr = M - 1;
      const char* src = (const char*)A + (size_t)gr * (K1 * 2) +
                        (size_t)((pc ^ (r & 7)) * 16);
      char* dst = xtile + (size_t)(w * PERW + i) * 16;
      __builtin_amdgcn_global_load_lds(
          (const __attribute__((address_space(1))) void*)src,
          (__attribute__((address_space(3))) void*)dst, 16, 0, 0);
    }
  }
  __syncthreads();

  // ---- GEMM 1: K=256, N=128 (4 waves x CT=2) -> h1t ----
  {
    const __hip_bfloat16* bbase = Bp1 + ((size_t)(w * 2) * 8 * 64 + (size_t)lane) * 8;
    f32x4 accs[2][2];
#pragma unroll
    for (int tt = 0; tt < 2; ++tt)
#pragma unroll
      for (int cc = 0; cc < 2; ++cc) accs[tt][cc] = (f32x4){0, 0, 0, 0};
#pragma unroll
    for (int ks = 0; ks < 8; ++ks) {
      bf16x8 a[2];
#pragma unroll
      for (int tt = 0; tt < 2; ++tt) {
        int r = tt * 16 + m;
        int c = ks * 4 + g;
        a[tt] = *(const bf16x8*)(xtile + (size_t)r * (K1 * 2) +
                                 (size_t)((c ^ (r & 7)) * 16));
      }
      const __hip_bfloat16* bb = bbase + (size_t)ks * 64 * 8;
#pragma unroll
      for (int cc = 0; cc < 2; ++cc) {
        bf16x8 b = *(const bf16x8*)(bb + (size_t)cc * 8 * 64 * 8);
#pragma unroll
        for (int tt = 0; tt < 2; ++tt)
          accs[tt][cc] = __builtin_amdgcn_mfma_f32_16x16x32_bf16(a[tt], b, accs[tt][cc], 0, 0, 0);
      }
    }
    float bv[2];
#pragma unroll
    for (int cc = 0; cc < 2; ++cc)
      bv[cc] = loadF(b1, (size_t)((w * 2 + cc) * 16 + m), f32);
#pragma unroll
    for (int tt = 0; tt < 2; ++tt) {
#pragma unroll
      for (int r = 0; r < 4; ++r) {
        int row = tt * 16 + g * 4 + r;
#pragma unroll
        for (int cc = 0; cc < 2; ++cc) {
          float v = lk(accs[tt][cc][r] + bv[cc]);
          int colb = ((w * 2 + cc) * 16 + m) * 2;     // byte within row
          int ch = colb >> 4, off = colb & 15;
          *(__hip_bfloat16*)(h1t + (size_t)row * 256 +
                             (size_t)((ch ^ (row & 7)) * 16) + off) =
              __float2bfloat16(v);
        }
      }
    }
  }
  __syncthreads();

  // ---- GEMM 2: K=128, N=64 (4 waves x CT=1) -> h2t ----
  {
    const __hip_bfloat16* bbase = Bp2 + ((size_t)w * 4 * 64 + (size_t)lane) * 8;
    f32x4 accs[2];
    accs[0] = (f32x4){0, 0, 0, 0};
    accs[1] = (f32x4){0, 0, 0, 0};
#pragma unroll
    for (int ks = 0; ks < 4; ++ks) {
      bf16x8 a[2];
#pragma unroll
      for (int tt = 0; tt < 2; ++tt) {
        int r = tt * 16 + m;
        int c = ks * 4 + g;
        a[tt] = *(const bf16x8*)(h1t + (size_t)r * 256 +
                                 (size_t)((c ^ (r & 7)) * 16));
      }
      const __hip_bfloat16* bb = bbase + (size_t)ks * 64 * 8;
      bf16x8 b = *(const bf16x8*)bb;
#pragma unroll
      for (int tt = 0; tt < 2; ++tt)
        accs[tt] = __builtin_amdgcn_mfma_f32_16x16x32_bf16(a[tt], b, accs[tt], 0, 0, 0);
    }
    float bv = loadF(b2, (size_t)(w * 16 + m), f32);
#pragma unroll
    for (int tt = 0; tt < 2; ++tt) {
#pragma unroll
      for (int r = 0; r < 4; ++r) {
        int row = tt * 16 + g * 4 + r;
        float v = lk(accs[tt][r] + bv);
        int colb = (w * 16 + m) * 2;
        int ch = colb >> 4, off = colb & 15;
        *(__hip_bfloat16*)(h2t + (size_t)row * 128 +
                           (size_t)((ch ^ (row & 7)) * 16) + off) =
            __float2bfloat16(v);
      }
    }
  }
  __syncthreads();

  // ---- GEMM 3: K=64, N=64 (4 waves x CT=1) -> y = bf16(acc * dinv) ----
  {
    const __hip_bfloat16* bbase = BpG + ((size_t)w * 2 * 64 + (size_t)lane) * 8;
    f32x4 accs[2];
    accs[0] = (f32x4){0, 0, 0, 0};
    accs[1] = (f32x4){0, 0, 0, 0};
#pragma unroll
    for (int ks = 0; ks < 2; ++ks) {
      bf16x8 a[2];
#pragma unroll
      for (int tt = 0; tt < 2; ++tt) {
        int r = tt * 16 + m;
        int c = ks * 4 + g;
        a[tt] = *(const bf16x8*)(h2t + (size_t)r * 128 +
                                 (size_t)((c ^ (r & 7)) * 16));
      }
      const __hip_bfloat16* bb = bbase + (size_t)ks * 64 * 8;
      bf16x8 b = *(const bf16x8*)bb;
#pragma unroll
      for (int tt = 0; tt < 2; ++tt)
        accs[tt] = __builtin_amdgcn_mfma_f32_16x16x32_bf16(a[tt], b, accs[tt], 0, 0, 0);
    }
#pragma unroll
    for (int tt = 0; tt < 2; ++tt) {
#pragma unroll
      for (int r = 0; r < 4; ++r) {
        int ro = row0 + tt * 16 + g * 4 + r;
        if (ro < M) {
          int col = w * 16 + m;
          Yout[(size_t)ro * 64 + col] = __float2bfloat16(accs[tt][r] * dinv[ro]);
        }
      }
    }
  }
}

// ---- CSR build pass A: LDS-staged binning, batched stream flush -------------
// LDS: bcnt[NB] | gbase[NB] | bins[NB*LCAP] (int2)
__global__ __launch_bounds__(256) void bin_kernel(const int* __restrict__ ei,
                                                  int* __restrict__ cur,
                                                  int2* __restrict__ rec,
                                                  int E, int NB,
                                                  const int* __restrict__ flags) {
  extern __shared__ int lds[];
  int* bcnt = lds;
  int* gbase = lds + NB;
  int2* bins = (int2*)(lds + 2 * NB);
  int i64 = flags[1] == 0;
  // real XCD id (hwreg 20); any value is correctness-safe after &7
  int stripe = __builtin_amdgcn_s_getreg(63508) & (NSTR - 1);
  int t = threadIdx.x;
  const int perRound = 256 * KEDGE;
  for (int base = blockIdx.x * perRound; base < E; base += gridDim.x * perRound) {
    for (int b = t; b < NB; b += 256) bcnt[b] = 0;
    __syncthreads();
    // bin into LDS
#pragma unroll 1
    for (int k = 0; k < KEDGE; ++k) {
      int i = base + k * 256 + t;
      if (i < E) {
        int r, c;
        if (i64) {
          r = ((const int2*)ei)[i].x;            // int64 low word
          c = ((const int2*)ei)[(size_t)E + i].x;
        } else {
          r = ei[i];
          c = ei[(size_t)E + i];
        }
        int b = c >> BSHIFT;
        int pos = atomicAdd(&bcnt[b], 1);
        if (pos < LCAP) {
          bins[b * LCAP + pos] = make_int2(r, c);
        } else {                                   // rare overflow: direct append
          int bs = b * NSTR + stripe;
          int slot = atomicAdd(&cur[bs], 1);
          if (slot < BCAP) rec[(size_t)bs * BCAP + slot] = make_int2(r, c);
        }
      }
    }
    __syncthreads();
    // reserve stream ranges (parallel atomics, no serialized chain)
    for (int b = t; b < NB; b += 256) {
      int n = min(bcnt[b], LCAP);
      if (n > 0) gbase[b] = atomicAdd(&cur[b * NSTR + stripe], n);
    }
    __syncthreads();
    // contiguous copy LDS -> stream
    int lane = t & 63, w = t >> 6;
    for (int b = w; b < NB; b += 4) {
      int n = min(bcnt[b], LCAP);
      if (n == 0) continue;
      int gb = gbase[b];
      size_t sb = (size_t)(b * NSTR + stripe) * BCAP;
      if (lane < n && gb + lane < BCAP)
        rec[sb + gb + lane] = bins[b * LCAP + lane];
    }
    __syncthreads();
  }
}

// Pass B: one block per bucket, 512 threads. Inline global prefix: base_b =
// sum_{i < b*NSTR} min(cur[i],BCAP) from the L2-hot cur array + LDS reduce.
__global__ __launch_bounds__(512) void place_kernel(const int2* __restrict__ rec,
                                                    const int* __restrict__ cur,
                                                    int* __restrict__ rowptr,
                                                    int* __restrict__ csr,
                                                    float* __restrict__ dinv, int Nn) {
  int b = blockIdx.x;
  int lo = b << BSHIFT;
  int t = threadIdx.x;
  __shared__ int cnt[BW];
  __shared__ int sc[BW];
  __shared__ int cursor[BW];
  __shared__ int red[512];
  int part = 0;
  for (int i = t; i < b * NSTR; i += 512) part += min(cur[i], BCAP);
  red[t] = part;
  if (t < BW) cnt[t] = 0;
  __syncthreads();
  for (int o = 256; o > 0; o >>= 1) {
    if (t < o) red[t] += red[t + o];
    __syncthreads();
  }
  int base = red[0];                    // global segment base for this bucket
#pragma unroll 1
  for (int s = 0; s < NSTR; ++s) {
    int n = min(cur[b * NSTR + s], BCAP);
    const int2* rp = rec + (size_t)(b * NSTR + s) * BCAP;
    for (int j = t; j < n; j += 512) atomicAdd(&cnt[rp[j].y - lo], 1);
  }
  __syncthreads();
  int v = 0;
  if (t < BW) { v = cnt[t]; sc[t] = v; }
  __syncthreads();
  for (int o = 1; o < BW; o <<= 1) {
    int a = (t >= o && t < BW) ? sc[t - o] : 0;
    __syncthreads();
    if (t < BW) sc[t] += a;
    __syncthreads();
  }
  if (t < BW) {
    int col = lo + t;
    if (col < Nn) {
      rowptr[col] = base + sc[t];               // segment END
      dinv[col] = rsqrtf((float)v + 1.0f);
    }
    cursor[t] = base + sc[t] - v;               // segment start
  }
  __syncthreads();
#pragma unroll 1
  for (int s = 0; s < NSTR; ++s) {
    int n = min(cur[b * NSTR + s], BCAP);
    const int2* rp = rec + (size_t)(b * NSTR + s) * BCAP;
    for (int j = t; j < n; j += 512) {
      int2 e = rp[j];
      int pos = atomicAdd(&cursor[e.y - lo], 1);
      csr[pos] = e.x;
    }
  }
}

// ---- gather core: aggregate y rows for one node (half-wave, shfl bcast) -----
__device__ __forceinline__ void gather_node(const unsigned* __restrict__ yu,
                                            const int* __restrict__ csr,
                                            int s, int e, int hl, int hb,
                                            float& acc0, float& acc1) {
  float p0a = 0, p1a = 0, p0b = 0, p1b = 0;
  float p0c = 0, p1c = 0, p0d = 0, p1d = 0;
  for (int base = s; base < e; base += 32) {
    int cnt = e - base; if (cnt > 32) cnt = 32;
    int rl = (base + hl < e) ? csr[base + hl] : 0;
    int j = 0;
    for (; j + 8 <= cnt; j += 8) {
      int r0 = __shfl(rl, hb + j + 0, 64);
      int r1 = __shfl(rl, hb + j + 1, 64);
      int r2 = __shfl(rl, hb + j + 2, 64);
      int r3 = __shfl(rl, hb + j + 3, 64);
      int r4 = __shfl(rl, hb + j + 4, 64);
      int r5 = __shfl(rl, hb + j + 5, 64);
      int r6 = __shfl(rl, hb + j + 6, 64);
      int r7 = __shfl(rl, hb + j + 7, 64);
      unsigned u0 = yu[(unsigned)r0 * 32u + hl];
      unsigned u1 = yu[(unsigned)r1 * 32u + hl];
      unsigned u2 = yu[(unsigned)r2 * 32u + hl];
      unsigned u3 = yu[(unsigned)r3 * 32u + hl];
      unsigned u4 = yu[(unsigned)r4 * 32u + hl];
      unsigned u5 = yu[(unsigned)r5 * 32u + hl];
      unsigned u6 = yu[(unsigned)r6 * 32u + hl];
      unsigned u7 = yu[(unsigned)r7 * 32u + hl];
      p0a += blo(u0); p1a += bhi(u0);
      p0b += blo(u1); p1b += bhi(u1);
      p0c += blo(u2); p1c += bhi(u2);
      p0d += blo(u3); p1d += bhi(u3);
      p0a += blo(u4); p1a += bhi(u4);
      p0b += blo(u5); p1b += bhi(u5);
      p0c += blo(u6); p1c += bhi(u6);
      p0d += blo(u7); p1d += bhi(u7);
    }
    for (; j + 4 <= cnt; j += 4) {
      int r0 = __shfl(rl, hb + j + 0, 64);
      int r1 = __shfl(rl, hb + j + 1, 64);
      int r2 = __shfl(rl, hb + j + 2, 64);
      int r3 = __shfl(rl, hb + j + 3, 64);
      unsigned u0 = yu[(unsigned)r0 * 32u + hl];
      unsigned u1 = yu[(unsigned)r1 * 32u + hl];
      unsigned u2 = yu[(unsigned)r2 * 32u + hl];
      unsigned u3 = yu[(unsigned)r3 * 32u + hl];
      p0a += blo(u0); p1a += bhi(u0);
      p0b += blo(u1); p1b += bhi(u1);
      p0c += blo(u2); p1c += bhi(u2);
      p0d += blo(u3); p1d += bhi(u3);
    }
    for (; j < cnt; ++j) {
      int r0 = __shfl(rl, hb + j, 64);
      unsigned u0 = yu[(unsigned)r0 * 32u + hl];
      p0a += blo(u0); p1a += bhi(u0);
    }
  }
  acc0 = (p0a + p0b) + (p0c + p0d);
  acc1 = (p1a + p1b) + (p1c + p1d);
}

// ---- FUSED gather(GCN1 agg) + GCN2 premul: y2 = bf16(h3 @ G2 * dinv) --------
// Block = 32 nodes. 8 half-waves gather 4 nodes each -> h3 tile in LDS (4KB,
// XOR swizzle) -> barrier -> MFMA K=64 with pG2 -> y2 = bf16(acc*dinv). h3
// never touches HBM.
__global__ __launch_bounds__(256) void gather_gemm(const __hip_bfloat16* __restrict__ y,
                                                   const int* __restrict__ csr,
                                                   const int* __restrict__ rowptr,
                                                   const float* __restrict__ dinv,
                                                   const void* __restrict__ bias,
                                                   const __hip_bfloat16* __restrict__ BpG,
                                                   __hip_bfloat16* __restrict__ Y2,
                                                   int Nn, const int* __restrict__ flags) {
  __shared__ char h3t[32 * 64 * 2];     // 4 KB
  int f32 = flags[0] != 0;
  int tid = threadIdx.x;
  int lane = tid & 63;
  int hl = lane & 31;
  int hb = (lane >> 5) << 5;            // shfl base (0 or 32)
  int hw = tid >> 5;                    // half-wave id 0..7
  int row0 = blockIdx.x << 5;
  const unsigned* yu = (const unsigned*)y;
  int f = hl * 2;
  float bv0 = loadF(bias, (size_t)f, f32);
  float bv1 = loadF(bias, (size_t)(f + 1), f32);

#pragma unroll 1
  for (int k = 0; k < 4; ++k) {
    int node = row0 + hw + 8 * k;
    int alive = node < Nn;
    int nd = alive ? node : Nn - 1;
    int s = (nd == 0) ? 0 : rowptr[nd - 1];
    int e = rowptr[nd];
    if (!alive) e = s;
    float acc0, acc1;
    gather_node(yu, csr, s, e, hl, hb, acc0, acc1);
    unsigned un = yu[(unsigned)nd * 32u + hl];   // self term: y[node]*di
    acc0 += blo(un); acc1 += bhi(un);
    float di = dinv[nd];
    float v0 = lk(di * acc0 + bv0);
    float v1 = lk(di * acc1 + bv1);
    // h3 bf16 pair -> LDS (chunk-XOR swizzle), row = node - row0
    int row = hw + 8 * k;
    union { unsigned u; unsigned short ss[2]; } pk;
    pk.ss[0] = (unsigned short)f2b(v0);
    pk.ss[1] = (unsigned short)f2b(v1);
    int colb = f * 2;                   // byte offset in row (4*hl)
    int ch = colb >> 4, off = colb & 15;
    *(unsigned*)(h3t + (size_t)row * 128 + (size_t)((ch ^ (row & 7)) * 16) + off) = pk.u;
  }
  __syncthreads();

  // MFMA: K=64, N=64 (4 waves x CT=1)
  int w = tid >> 6;
  int m = lane & 15, g = lane >> 4;
  const __hip_bfloat16* bbase = BpG + ((size_t)w * 2 * 64 + (size_t)lane) * 8;
  f32x4 accs[2];
  accs[0] = (f32x4){0, 0, 0, 0};
  accs[1] = (f32x4){0, 0, 0, 0};
#pragma unroll
  for (int ks = 0; ks < 2; ++ks) {
    bf16x8 a[2];
#pragma unroll
    for (int tt = 0; tt < 2; ++tt) {
      int r = tt * 16 + m;
      int c = ks * 4 + g;
      a[tt] = *(const bf16x8*)(h3t + (size_t)r * 128 +
                               (size_t)((c ^ (r & 7)) * 16));
    }
    const __hip_bfloat16* bb = bbase + (size_t)ks * 64 * 8;
    bf16x8 b = *(const bf16x8*)bb;
#pragma unroll
    for (int tt = 0; tt < 2; ++tt)
      accs[tt] = __builtin_amdgcn_mfma_f32_16x16x32_bf16(a[tt], b, accs[tt], 0, 0, 0);
  }
#pragma unroll
  for (int tt = 0; tt < 2; ++tt) {
#pragma unroll
    for (int r = 0; r < 4; ++r) {
      int ro = row0 + tt * 16 + g * 4 + r;
      if (ro < Nn) {
        int col = w * 16 + m;
        Y2[(size_t)ro * 64 + col] = __float2bfloat16(accs[tt][r] * dinv[ro]);
      }
    }
  }
}

// ---- final gather: h out + per-node edge-head scores ------------------------
// Half-wave (32 lanes) per node; coalesced csr window + shfl broadcast.
__global__ __launch_bounds__(256) void gather_kernel(const __hip_bfloat16* __restrict__ y,
                                                     const int* __restrict__ csr,
                                                     const int* __restrict__ rowptr,
                                                     const float* __restrict__ dinv,
                                                     const void* __restrict__ bias,
                                                     void* __restrict__ outp, size_t obase,
                                                     int Nn,
                                                     float* __restrict__ ssrc,
                                                     float* __restrict__ sdst,
                                                     const void* __restrict__ Wp,
                                                     const int* __restrict__ flags) {
  int f32 = flags[0] != 0;
  int lane = threadIdx.x & 63;
  int w = (blockIdx.x * blockDim.x + threadIdx.x) >> 6;
  if (2 * w >= Nn) return;
  int half = lane >> 5;
  int hl = lane & 31;
  int hb = half << 5;
  int node = 2 * w + half;
  int alive = node < Nn;
  int nd = alive ? node : Nn - 1;
  int s = (nd == 0) ? 0 : rowptr[nd - 1];
  int e = rowptr[nd];
  if (!alive) e = s;
  const unsigned* yu = (const unsigned*)y;
  float acc0, acc1;
  gather_node(yu, csr, s, e, hl, hb, acc0, acc1);
  unsigned un = yu[(unsigned)nd * 32u + hl];   // self term: y[node]*di
  acc0 += blo(un); acc1 += bhi(un);
  float di = dinv[nd];
  int f = hl * 2;
  float v0 = lk(di * acc0 + loadF(bias, (size_t)f, f32));
  float v1 = lk(di * acc1 + loadF(bias, (size_t)(f + 1), f32));
  if (alive) {
    if (f32) {
      *(float2*)((float*)outp + obase + (size_t)node * 64 + f) = make_float2(v0, v1);
    } else {
      union { unsigned u; unsigned short ss[2]; } pk;
      pk.ss[0] = (unsigned short)f2b(v0);
      pk.ss[1] = (unsigned short)f2b(v1);
      *(unsigned*)((__hip_bfloat16*)outp + obase + (size_t)node * 64 + f) = pk.u;
    }
  }
  float q1 = v0 * loadF(Wp, (size_t)f, f32) + v1 * loadF(Wp, (size_t)(f + 1), f32);
  float q2 = v0 * loadF(Wp, (size_t)(64 + f), f32) + v1 * loadF(Wp, (size_t)(65 + f), f32);
#pragma unroll
  for (int o = 16; o > 0; o >>= 1) {        // reduce within each 32-lane half
    q1 += __shfl_down(q1, o, 64);
    q2 += __shfl_down(q2, o, 64);
  }
  if (hl == 0 && alive) { ssrc[node] = q1; sdst[node] = q2; }
}

// ---- edge scoring head: one THREAD per edge, scores precomputed -------------
__global__ __launch_bounds__(256) void edge_head_kernel(void* __restrict__ dout,
                                                        const int* __restrict__ eli,
                                                        const void* __restrict__ ea,
                                                        const float* __restrict__ ssrc,
                                                        const float* __restrict__ sdst,
                                                        const void* __restrict__ Wp,
                                                        const void* __restrict__ bp,
                                                        int EL, const int* __restrict__ flags) {
  int f32 = flags[0] != 0;
  int i64 = flags[1] == 0;
  int tid = blockIdx.x * blockDim.x + threadIdx.x;
  if (tid >= EL) return;
  int s, d;
  if (i64) {
    s = ((const int2*)eli)[tid].x;              // int64 low word, single 8B load
    d = ((const int2*)eli)[(size_t)EL + tid].x;
  } else {
    s = eli[tid];
    d = eli[(size_t)EL + tid];
  }
  float acc = ssrc[s] + sdst[d] + loadF(bp, 0, f32);
  if (f32) {
    const float* eap = (const float*)ea + (size_t)tid * 8;
    float4 u0 = *(const float4*)eap;
    float4 u1 = *(const float4*)(eap + 4);
    acc += u0.x * loadF(Wp, 128, 1) + u0.y * loadF(Wp, 129, 1) +
           u0.z * loadF(Wp, 130, 1) + u0.w * loadF(Wp, 131, 1) +
           u1.x * loadF(Wp, 132, 1) + u1.y * loadF(Wp, 133, 1) +
           u1.z * loadF(Wp, 134, 1) + u1.w * loadF(Wp, 135, 1);
  } else {
    bf16x8 u = *(const bf16x8*)((const __hip_bfloat16*)ea + (size_t)tid * 8);
#pragma unroll
    for (int j = 0; j < 8; ++j) {
      union { short s; __hip_bfloat16 h; } cv; cv.s = u[j];
      acc += __bfloat162float(cv.h) * loadF(Wp, (size_t)(128 + j), 0);
    }
  }
  storeF(dout, (size_t)tid, f32, acc);
}

extern "C" void kernel_launch(void* const* d_in, const int* in_sizes, int n_in,
                              void* d_out, int out_size, void* d_ws, size_t ws_size,
                              hipStream_t stream) {
  const void* x   = d_in[0];
  const int* ei   = (const int*)d_in[1];
  const int* eli  = (const int*)d_in[2];
  const void* ea  = d_in[3];
  const void* W1  = d_in[4];
  const void* b1  = d_in[5];
  const void* W2  = d_in[6];
  const void* b2  = d_in[7];
  const void* Wg1 = d_in[8];
  const void* bg1 = d_in[9];
  const void* Wg2 = d_in[10];
  const void* bg2 = d_in[11];
  const void* Wp  = d_in[12];
  const void* bp  = d_in[13];

  const int Nn = in_sizes[0] / 256;
  const int E  = in_sizes[1] / 2;
  const int EL = in_sizes[2] / 2;
  const int NB = (Nn + BW - 1) >> BSHIFT;       // col buckets

  char* ws = (char*)d_ws;
  size_t off = 0;
  auto take = [&](size_t bytes) -> char* {
    char* p = ws + off;
    off = (off + bytes + 255) & ~(size_t)255;
    return p;
  };
  int*   flags  = (int*)take(256);
  int*   cur    = (int*)take((size_t)NB * NSTR * 4);   // contiguous after flags
  int*   rowptr = (int*)take((size_t)Nn * 4);
  float* dinv   = (float*)take((size_t)Nn * 4);
  float* ssrc   = (float*)take((size_t)Nn * 4);
  float* sdst   = (float*)take((size_t)Nn * 4);
  int*   csr    = (int*)take((size_t)E * 4);
  int2*  rec    = (int2*)take((size_t)NB * NSTR * BCAP * 8);
  __hip_bfloat16* pW1 = (__hip_bfloat16*)take(256 * 128 * 2);
  __hip_bfloat16* pW2 = (__hip_bfloat16*)take(128 * 64 * 2);
  __hip_bfloat16* pG1 = (__hip_bfloat16*)take(64 * 64 * 2);
  __hip_bfloat16* pG2 = (__hip_bfloat16*)take(64 * 64 * 2);
  __hip_bfloat16* y  = (__hip_bfloat16*)take((size_t)Nn * 64 * 2);
  __hip_bfloat16* y2 = (__hip_bfloat16*)take((size_t)Nn * 64 * 2);

  // flags + cur are contiguous -> one memset covers both
  hipMemsetAsync(flags, 0, 256 + (((size_t)NB * NSTR * 4 + 255) & ~(size_t)255), stream);
  detect_kernel<<<1, 256, 0, stream>>>((const unsigned short*)x, ei, flags);

  pack_all<<<96, 64, 0, stream>>>(W1, W2, Wg1, Wg2, pW1, pW2, pG1, pG2, flags);

  // CSR build: LDS-staged binning -> place (scan fused into place)
  const int ldsbytes = NB * (8 + LCAP * 8);     // bcnt + gbase + bins
  const int nbin = (E + 256 * KEDGE - 1) / (256 * KEDGE);
  bin_kernel<<<nbin, 256, ldsbytes, stream>>>(ei, cur, rec, E, NB, flags);
  place_kernel<<<NB, 512, 0, stream>>>(rec, cur, rowptr, csr, dinv, Nn);

  // fused MLP + GCN1 premul: x -> y, one dispatch
  const int tblocks = (Nn + 31) / 32;
  gemm_fused123<<<tblocks, 256, 0, stream>>>(x, pW1, b1, pW2, b2, pG1, dinv, y,
                                             Nn, flags);

  // fused gather(GCN1) + GCN2 premul: y -> y2, one dispatch
  gather_gemm<<<tblocks, 256, 0, stream>>>(y, csr, rowptr, dinv, bg1, pG2, y2,
                                           Nn, flags);

  // final gather: h out + edge-head scores
  const int gwaves = (Nn + 1) / 2;
  const int gblocks = (gwaves + 3) / 4;
  gather_kernel<<<gblocks, 256, 0, stream>>>(y2, csr, rowptr, dinv, bg2,
                                             d_out, (size_t)EL, Nn,
                                             ssrc, sdst, Wp, flags);

  edge_head_kernel<<<(EL + 255) / 256, 256, 0, stream>>>(d_out, eli, ea, ssrc, sdst,
                                                         Wp, bp, EL, flags);
}